// Round 1
// baseline (835.429 us; speedup 1.0000x reference)
//
#include <hip/hip_runtime.h>
#include <hip/hip_bf16.h>

// Problem: B=16, Q=2048, K=2048, D=512, fp32 in/out.
// d_out = [context (16*2048*512) | attention_weights (16*2048*2048)] fp32.
// Strategy: fp16 MFMA (16x16x32) for all three GEMMs; fp32 accum; scores
// materialized directly into d_out weights region; in-place softmax; context
// GEMM reads softmaxed weights back. fp16 (not bf16) keeps score abs-error
// ~0.03 << 0.104 threshold despite sigma~22.6 score scale.

#define B_ 16
#define Q_ 2048
#define K_ 2048
#define D_ 512

typedef _Float16 half8  __attribute__((ext_vector_type(8)));
typedef _Float16 half4v __attribute__((ext_vector_type(4)));
typedef float    floatx4 __attribute__((ext_vector_type(4)));

__device__ __forceinline__ void gld16(const _Float16* g, _Float16* l) {
  // async global->LDS, 16B per lane; LDS dest must be wave-base + lane*16
  __builtin_amdgcn_global_load_lds(
      (const __attribute__((address_space(1))) void*)g,
      (__attribute__((address_space(3))) void*)l, 16, 0, 0);
}

// ---------------------------------------------------------------------------
// GEMM C[M,N] = A[M,Kd] * B[N,Kd]^T, A,B fp16 global, 128x128 tile, BK=32.
// m97 structure: global_load_lds staging, 2-barrier K-loop, 4x4 MFMA per wave.
// ---------------------------------------------------------------------------
template <bool OUT_HALF>
__global__ __launch_bounds__(256, 2)
void gemm_bt_f16(const _Float16* __restrict__ A, const _Float16* __restrict__ Bm,
                 void* __restrict__ Cv, int M, int N, int Kd,
                 long sA, long sB, long sC)
{
  const int b  = blockIdx.z;
  const _Float16* Ab = A + (long)b * sA;
  const _Float16* Bb = Bm + (long)b * sB;
  const int m0 = blockIdx.y * 128, n0 = blockIdx.x * 128;

  __shared__ _Float16 As[128 * 32];
  __shared__ _Float16 Bs[128 * 32];

  const int tid = threadIdx.x, wave = tid >> 6, lane = tid & 63;
  const int wm = wave >> 1, wn = wave & 1;
  floatx4 acc[4][4] = {};

  // staging: wave w, lane l -> row (w*16 + l/4), k-chunk (l%4)*8 (chunk0 rows 0-63, chunk1 rows 64-127)
  const int srow = wave * 16 + (lane >> 2);
  const int skof = (lane & 3) * 8;
  _Float16* la0 = As + wave * 512 + lane * 8;
  _Float16* la1 = la0 + 2048;
  _Float16* lb0 = Bs + wave * 512 + lane * 8;
  _Float16* lb1 = lb0 + 2048;
  const _Float16* ga = Ab + (long)(m0 + srow) * Kd + skof;
  const _Float16* gb = Bb + (long)(n0 + srow) * Kd + skof;

  const int fr = lane & 15, fk = (lane >> 4) * 8;

  for (int k0 = 0; k0 < Kd; k0 += 32) {
    gld16(ga + k0, la0);
    gld16(ga + 64l * Kd + k0, la1);
    gld16(gb + k0, lb0);
    gld16(gb + 64l * Kd + k0, lb1);
    __syncthreads();   // drains vmcnt -> LDS tiles ready

    half8 af[4], bf[4];
#pragma unroll
    for (int t = 0; t < 4; t++) {
      af[t] = *(const half8*)(As + (wm * 64 + t * 16 + fr) * 32 + fk);
      bf[t] = *(const half8*)(Bs + (wn * 64 + t * 16 + fr) * 32 + fk);
    }
#pragma unroll
    for (int mt = 0; mt < 4; mt++)
#pragma unroll
      for (int nt = 0; nt < 4; nt++)
        acc[mt][nt] = __builtin_amdgcn_mfma_f32_16x16x32_f16(af[mt], bf[nt], acc[mt][nt], 0, 0, 0);
    __syncthreads();   // LDS reads done before next stage overwrites
  }

  // C/D layout: col = lane&15, row = (lane>>4)*4 + r  (verified m89/m91)
  const int orow = (lane >> 4) * 4, ocol = lane & 15;
  if constexpr (OUT_HALF) {
    _Float16* Cp = (_Float16*)Cv + (long)b * sC;
#pragma unroll
    for (int mt = 0; mt < 4; mt++)
#pragma unroll
      for (int nt = 0; nt < 4; nt++)
#pragma unroll
        for (int r = 0; r < 4; r++)
          Cp[(long)(m0 + wm * 64 + mt * 16 + orow + r) * N + (n0 + wn * 64 + nt * 16 + ocol)] =
              (_Float16)acc[mt][nt][r];
  } else {
    float* Cp = (float*)Cv + (long)b * sC;
#pragma unroll
    for (int mt = 0; mt < 4; mt++)
#pragma unroll
      for (int nt = 0; nt < 4; nt++)
#pragma unroll
        for (int r = 0; r < 4; r++)
          Cp[(long)(m0 + wm * 64 + mt * 16 + orow + r) * N + (n0 + wn * 64 + nt * 16 + ocol)] =
              acc[mt][nt][r];
  }
}

// ---------------------------------------------------------------------------
// GEMM with A fp32 in global (converted to fp16 during LDS staging),
// B fp16 (async staged). C = A[M,Kd] * B[N,Kd]^T. Used for keys & context.
// ---------------------------------------------------------------------------
template <bool OUT_HALF>
__global__ __launch_bounds__(256, 2)
void gemm_a32_bt(const float* __restrict__ A, const _Float16* __restrict__ Bm,
                 void* __restrict__ Cv, int M, int N, int Kd, int lda,
                 long sA, long sB, long sC)
{
  const int b  = blockIdx.z;
  const float*    Ab = A + (long)b * sA;
  const _Float16* Bb = Bm + (long)b * sB;
  const int m0 = blockIdx.y * 128, n0 = blockIdx.x * 128;

  __shared__ _Float16 As[128 * 32];
  __shared__ _Float16 Bs[128 * 32];

  const int tid = threadIdx.x, wave = tid >> 6, lane = tid & 63;
  const int wm = wave >> 1, wn = wave & 1;
  floatx4 acc[4][4] = {};

  // B async staging (same as gemm_bt_f16)
  const int srow = wave * 16 + (lane >> 2);
  const int skof = (lane & 3) * 8;
  _Float16* lb0 = Bs + wave * 512 + lane * 8;
  _Float16* lb1 = lb0 + 2048;
  const _Float16* gb = Bb + (long)(n0 + srow) * Kd + skof;

  // A staging: thread t -> row t/2, k-chunk (t&1)*16 (16 fp32 -> 16 fp16)
  const int arow = tid >> 1, akc = (tid & 1) * 16;
  const float* ga = Ab + (long)(m0 + arow) * lda + akc;

  const int fr = lane & 15, fk = (lane >> 4) * 8;

  for (int k0 = 0; k0 < Kd; k0 += 32) {
    gld16(gb + k0, lb0);
    gld16(gb + 64l * Kd + k0, lb1);

    const float* ap = ga + k0;
    float4 f0 = *(const float4*)(ap);
    float4 f1 = *(const float4*)(ap + 4);
    float4 f2 = *(const float4*)(ap + 8);
    float4 f3 = *(const float4*)(ap + 12);
    half8 h0, h1;
    h0[0] = (_Float16)f0.x; h0[1] = (_Float16)f0.y; h0[2] = (_Float16)f0.z; h0[3] = (_Float16)f0.w;
    h0[4] = (_Float16)f1.x; h0[5] = (_Float16)f1.y; h0[6] = (_Float16)f1.z; h0[7] = (_Float16)f1.w;
    h1[0] = (_Float16)f2.x; h1[1] = (_Float16)f2.y; h1[2] = (_Float16)f2.z; h1[3] = (_Float16)f2.w;
    h1[4] = (_Float16)f3.x; h1[5] = (_Float16)f3.y; h1[6] = (_Float16)f3.z; h1[7] = (_Float16)f3.w;
    *(half8*)(As + arow * 32 + akc)     = h0;
    *(half8*)(As + arow * 32 + akc + 8) = h1;

    __syncthreads();

    half8 af[4], bf[4];
#pragma unroll
    for (int t = 0; t < 4; t++) {
      af[t] = *(const half8*)(As + (wm * 64 + t * 16 + fr) * 32 + fk);
      bf[t] = *(const half8*)(Bs + (wn * 64 + t * 16 + fr) * 32 + fk);
    }
#pragma unroll
    for (int mt = 0; mt < 4; mt++)
#pragma unroll
      for (int nt = 0; nt < 4; nt++)
        acc[mt][nt] = __builtin_amdgcn_mfma_f32_16x16x32_f16(af[mt], bf[nt], acc[mt][nt], 0, 0, 0);
    __syncthreads();
  }

  const int orow = (lane >> 4) * 4, ocol = lane & 15;
  if constexpr (OUT_HALF) {
    _Float16* Cp = (_Float16*)Cv + (long)b * sC;
#pragma unroll
    for (int mt = 0; mt < 4; mt++)
#pragma unroll
      for (int nt = 0; nt < 4; nt++)
#pragma unroll
        for (int r = 0; r < 4; r++)
          Cp[(long)(m0 + wm * 64 + mt * 16 + orow + r) * N + (n0 + wn * 64 + nt * 16 + ocol)] =
              (_Float16)acc[mt][nt][r];
  } else {
    float* Cp = (float*)Cv + (long)b * sC;
#pragma unroll
    for (int mt = 0; mt < 4; mt++)
#pragma unroll
      for (int nt = 0; nt < 4; nt++)
#pragma unroll
        for (int r = 0; r < 4; r++)
          Cp[(long)(m0 + wm * 64 + mt * 16 + orow + r) * N + (n0 + wn * 64 + nt * 16 + ocol)] =
              acc[mt][nt][r];
  }
}

// ---------------------------------------------------------------------------
// In-place row softmax: one block per row of 2048 fp32; 8 elems/thread in regs.
// ---------------------------------------------------------------------------
__global__ __launch_bounds__(256)
void softmax_rows(float* __restrict__ S)
{
  float* p = S + (long)blockIdx.x * 2048;
  const int tid = threadIdx.x, lane = tid & 63, wave = tid >> 6;

  float4 v0 = *(const float4*)(p + tid * 4);
  float4 v1 = *(const float4*)(p + 1024 + tid * 4);

  float mx = fmaxf(fmaxf(fmaxf(v0.x, v0.y), fmaxf(v0.z, v0.w)),
                   fmaxf(fmaxf(v1.x, v1.y), fmaxf(v1.z, v1.w)));
#pragma unroll
  for (int off = 32; off; off >>= 1) mx = fmaxf(mx, __shfl_down(mx, off, 64));

  __shared__ float red[8];
  if (lane == 0) red[wave] = mx;
  __syncthreads();
  mx = fmaxf(fmaxf(red[0], red[1]), fmaxf(red[2], red[3]));

  v0.x = __expf(v0.x - mx); v0.y = __expf(v0.y - mx);
  v0.z = __expf(v0.z - mx); v0.w = __expf(v0.w - mx);
  v1.x = __expf(v1.x - mx); v1.y = __expf(v1.y - mx);
  v1.z = __expf(v1.z - mx); v1.w = __expf(v1.w - mx);

  float s = v0.x + v0.y + v0.z + v0.w + v1.x + v1.y + v1.z + v1.w;
#pragma unroll
  for (int off = 32; off; off >>= 1) s += __shfl_down(s, off, 64);
  if (lane == 0) red[4 + wave] = s;
  __syncthreads();
  s = red[4] + red[5] + red[6] + red[7];

  float inv = 1.0f / s;
  v0.x *= inv; v0.y *= inv; v0.z *= inv; v0.w *= inv;
  v1.x *= inv; v1.y *= inv; v1.z *= inv; v1.w *= inv;
  *(float4*)(p + tid * 4) = v0;
  *(float4*)(p + 1024 + tid * 4) = v1;
}

// fp32 -> fp16 converts -------------------------------------------------------
__global__ __launch_bounds__(256)
void convert_q(const float4* __restrict__ q, half4v* __restrict__ qh)
{
  long i = (long)blockIdx.x * 256 + threadIdx.x;
  float4 a = q[i];
  half4v h;
  h[0] = (_Float16)a.x; h[1] = (_Float16)a.y; h[2] = (_Float16)a.z; h[3] = (_Float16)a.w;
  qh[i] = h;
}

// V transpose: v[b][k][e] fp32 -> vt[b][e][k] fp16 (for BT-layout context GEMM)
__global__ __launch_bounds__(256)
void transpose_v(const float* __restrict__ v, _Float16* __restrict__ vt)
{
  __shared__ float tile[32][33];
  const int b = blockIdx.z, kk = blockIdx.y * 32, ee = blockIdx.x * 32;
  const float* vp = v + (long)b * K_ * D_;
  _Float16* vtp = vt + (long)b * D_ * K_;
  const int tx = threadIdx.x & 31, ty = threadIdx.x >> 5;  // ty 0..7
#pragma unroll
  for (int i = 0; i < 32; i += 8)
    tile[ty + i][tx] = vp[(long)(kk + ty + i) * D_ + ee + tx];
  __syncthreads();
#pragma unroll
  for (int i = 0; i < 32; i += 8)
    vtp[(long)(ee + ty + i) * K_ + kk + tx] = (_Float16)tile[tx][ty + i];
}

// ---------------------------------------------------------------------------
extern "C" void kernel_launch(void* const* d_in, const int* in_sizes, int n_in,
                              void* d_out, int out_size, void* d_ws, size_t ws_size,
                              hipStream_t stream)
{
  const float* q = (const float*)d_in[0];   // [16,2048,512]
  const float* v = (const float*)d_in[1];   // [16,2048,512]
  const float* w = (const float*)d_in[2];   // [512,512]

  float* ctx    = (float*)d_out;                       // [16,2048,512]
  float* scores = ctx + (long)B_ * Q_ * D_;            // [16,2048,2048]

  // workspace layout (halfs): q_h | keys_h | vt_h | w_h  (~101 MB total)
  _Float16* qh  = (_Float16*)d_ws;
  _Float16* kh  = qh  + (long)B_ * Q_ * D_;
  _Float16* vth = kh  + (long)B_ * K_ * D_;
  _Float16* wh  = vth + (long)B_ * D_ * K_;

  // 1. converts + transpose
  convert_q<<<16384, 256, 0, stream>>>((const float4*)q, (half4v*)qh);
  convert_q<<<256,   256, 0, stream>>>((const float4*)w, (half4v*)wh);
  transpose_v<<<dim3(D_ / 32, K_ / 32, B_), 256, 0, stream>>>(v, vth);

  // 2. keys[b] = v[b] (2048x512) * W^T (512x512) -> fp16
  gemm_a32_bt<true><<<dim3(D_ / 128, K_ / 128, B_), 256, 0, stream>>>(
      v, wh, kh, K_, D_, D_, D_, (long)K_ * D_, 0l, (long)K_ * D_);

  // 3. scores[b] = q[b] (2048x512) * keys[b]^T -> fp32 into d_out weights region
  gemm_bt_f16<false><<<dim3(K_ / 128, Q_ / 128, B_), 256, 0, stream>>>(
      qh, kh, scores, Q_, K_, D_, (long)Q_ * D_, (long)K_ * D_, (long)Q_ * K_);

  // 4. softmax over last dim, in place
  softmax_rows<<<B_ * Q_, 256, 0, stream>>>(scores);

  // 5. context[b] = P[b] (2048x2048 fp32) * vt[b]^T (512x2048 fp16) -> fp32
  gemm_a32_bt<false><<<dim3(D_ / 128, Q_ / 128, B_), 256, 0, stream>>>(
      scores, vth, ctx, Q_, D_, K_, K_, (long)Q_ * K_, (long)D_ * K_, (long)Q_ * D_);
}

// Round 2
// 788.880 us; speedup vs baseline: 1.0590x; 1.0590x over previous
//
#include <hip/hip_runtime.h>
#include <hip/hip_bf16.h>

// Problem: B=16, Q=2048, K=2048, D=512, fp32 in/out.
// d_out = [context (16*2048*512) | attention_weights (16*2048*2048)] fp32.
// R2: softmax emits fp16 P; context GEMM now pure-fp16 (gemm_bt_f16) instead
// of the latency-bound a32 convert-staging path (324 TF -> expect ~900 TF).
// Falls back to R1 a32 context path if ws_size < 168.3 MB.

#define B_ 16
#define Q_ 2048
#define K_ 2048
#define D_ 512

typedef _Float16 half8  __attribute__((ext_vector_type(8)));
typedef _Float16 half4v __attribute__((ext_vector_type(4)));
typedef float    floatx4 __attribute__((ext_vector_type(4)));

__device__ __forceinline__ void gld16(const _Float16* g, _Float16* l) {
  // async global->LDS, 16B per lane; LDS dest must be wave-base + lane*16
  __builtin_amdgcn_global_load_lds(
      (const __attribute__((address_space(1))) void*)g,
      (__attribute__((address_space(3))) void*)l, 16, 0, 0);
}

// ---------------------------------------------------------------------------
// GEMM C[M,N] = A[M,Kd] * B[N,Kd]^T, A,B fp16 global, 128x128 tile, BK=32.
// m97 structure: global_load_lds staging, 2-barrier K-loop, 4x4 MFMA per wave.
// ---------------------------------------------------------------------------
template <bool OUT_HALF>
__global__ __launch_bounds__(256, 2)
void gemm_bt_f16(const _Float16* __restrict__ A, const _Float16* __restrict__ Bm,
                 void* __restrict__ Cv, int M, int N, int Kd,
                 long sA, long sB, long sC)
{
  const int b  = blockIdx.z;
  const _Float16* Ab = A + (long)b * sA;
  const _Float16* Bb = Bm + (long)b * sB;
  const int m0 = blockIdx.y * 128, n0 = blockIdx.x * 128;

  __shared__ _Float16 As[128 * 32];
  __shared__ _Float16 Bs[128 * 32];

  const int tid = threadIdx.x, wave = tid >> 6, lane = tid & 63;
  const int wm = wave >> 1, wn = wave & 1;
  floatx4 acc[4][4] = {};

  // staging: wave w, lane l -> row (w*16 + l/4), k-chunk (l%4)*8
  const int srow = wave * 16 + (lane >> 2);
  const int skof = (lane & 3) * 8;
  _Float16* la0 = As + wave * 512 + lane * 8;
  _Float16* la1 = la0 + 2048;
  _Float16* lb0 = Bs + wave * 512 + lane * 8;
  _Float16* lb1 = lb0 + 2048;
  const _Float16* ga = Ab + (long)(m0 + srow) * Kd + skof;
  const _Float16* gb = Bb + (long)(n0 + srow) * Kd + skof;

  const int fr = lane & 15, fk = (lane >> 4) * 8;

  for (int k0 = 0; k0 < Kd; k0 += 32) {
    gld16(ga + k0, la0);
    gld16(ga + 64l * Kd + k0, la1);
    gld16(gb + k0, lb0);
    gld16(gb + 64l * Kd + k0, lb1);
    __syncthreads();   // drains vmcnt -> LDS tiles ready

    half8 af[4], bf[4];
#pragma unroll
    for (int t = 0; t < 4; t++) {
      af[t] = *(const half8*)(As + (wm * 64 + t * 16 + fr) * 32 + fk);
      bf[t] = *(const half8*)(Bs + (wn * 64 + t * 16 + fr) * 32 + fk);
    }
#pragma unroll
    for (int mt = 0; mt < 4; mt++)
#pragma unroll
      for (int nt = 0; nt < 4; nt++)
        acc[mt][nt] = __builtin_amdgcn_mfma_f32_16x16x32_f16(af[mt], bf[nt], acc[mt][nt], 0, 0, 0);
    __syncthreads();   // LDS reads done before next stage overwrites
  }

  // C/D layout: col = lane&15, row = (lane>>4)*4 + r  (verified m89/m91)
  const int orow = (lane >> 4) * 4, ocol = lane & 15;
  if constexpr (OUT_HALF) {
    _Float16* Cp = (_Float16*)Cv + (long)b * sC;
#pragma unroll
    for (int mt = 0; mt < 4; mt++)
#pragma unroll
      for (int nt = 0; nt < 4; nt++)
#pragma unroll
        for (int r = 0; r < 4; r++)
          Cp[(long)(m0 + wm * 64 + mt * 16 + orow + r) * N + (n0 + wn * 64 + nt * 16 + ocol)] =
              (_Float16)acc[mt][nt][r];
  } else {
    float* Cp = (float*)Cv + (long)b * sC;
#pragma unroll
    for (int mt = 0; mt < 4; mt++)
#pragma unroll
      for (int nt = 0; nt < 4; nt++)
#pragma unroll
        for (int r = 0; r < 4; r++)
          Cp[(long)(m0 + wm * 64 + mt * 16 + orow + r) * N + (n0 + wn * 64 + nt * 16 + ocol)] =
              acc[mt][nt][r];
  }
}

// ---------------------------------------------------------------------------
// GEMM with A fp32 in global (converted to fp16 during LDS staging),
// B fp16 (async staged). C = A[M,Kd] * B[N,Kd]^T. Keys GEMM + fallback.
// ---------------------------------------------------------------------------
template <bool OUT_HALF>
__global__ __launch_bounds__(256, 2)
void gemm_a32_bt(const float* __restrict__ A, const _Float16* __restrict__ Bm,
                 void* __restrict__ Cv, int M, int N, int Kd, int lda,
                 long sA, long sB, long sC)
{
  const int b  = blockIdx.z;
  const float*    Ab = A + (long)b * sA;
  const _Float16* Bb = Bm + (long)b * sB;
  const int m0 = blockIdx.y * 128, n0 = blockIdx.x * 128;

  __shared__ _Float16 As[128 * 32];
  __shared__ _Float16 Bs[128 * 32];

  const int tid = threadIdx.x, wave = tid >> 6, lane = tid & 63;
  const int wm = wave >> 1, wn = wave & 1;
  floatx4 acc[4][4] = {};

  const int srow = wave * 16 + (lane >> 2);
  const int skof = (lane & 3) * 8;
  _Float16* lb0 = Bs + wave * 512 + lane * 8;
  _Float16* lb1 = lb0 + 2048;
  const _Float16* gb = Bb + (long)(n0 + srow) * Kd + skof;

  const int arow = tid >> 1, akc = (tid & 1) * 16;
  const float* ga = Ab + (long)(m0 + arow) * lda + akc;

  const int fr = lane & 15, fk = (lane >> 4) * 8;

  for (int k0 = 0; k0 < Kd; k0 += 32) {
    gld16(gb + k0, lb0);
    gld16(gb + 64l * Kd + k0, lb1);

    const float* ap = ga + k0;
    float4 f0 = *(const float4*)(ap);
    float4 f1 = *(const float4*)(ap + 4);
    float4 f2 = *(const float4*)(ap + 8);
    float4 f3 = *(const float4*)(ap + 12);
    half8 h0, h1;
    h0[0] = (_Float16)f0.x; h0[1] = (_Float16)f0.y; h0[2] = (_Float16)f0.z; h0[3] = (_Float16)f0.w;
    h0[4] = (_Float16)f1.x; h0[5] = (_Float16)f1.y; h0[6] = (_Float16)f1.z; h0[7] = (_Float16)f1.w;
    h1[0] = (_Float16)f2.x; h1[1] = (_Float16)f2.y; h1[2] = (_Float16)f2.z; h1[3] = (_Float16)f2.w;
    h1[4] = (_Float16)f3.x; h1[5] = (_Float16)f3.y; h1[6] = (_Float16)f3.z; h1[7] = (_Float16)f3.w;
    *(half8*)(As + arow * 32 + akc)     = h0;
    *(half8*)(As + arow * 32 + akc + 8) = h1;

    __syncthreads();

    half8 af[4], bf[4];
#pragma unroll
    for (int t = 0; t < 4; t++) {
      af[t] = *(const half8*)(As + (wm * 64 + t * 16 + fr) * 32 + fk);
      bf[t] = *(const half8*)(Bs + (wn * 64 + t * 16 + fr) * 32 + fk);
    }
#pragma unroll
    for (int mt = 0; mt < 4; mt++)
#pragma unroll
      for (int nt = 0; nt < 4; nt++)
        acc[mt][nt] = __builtin_amdgcn_mfma_f32_16x16x32_f16(af[mt], bf[nt], acc[mt][nt], 0, 0, 0);
    __syncthreads();
  }

  const int orow = (lane >> 4) * 4, ocol = lane & 15;
  if constexpr (OUT_HALF) {
    _Float16* Cp = (_Float16*)Cv + (long)b * sC;
#pragma unroll
    for (int mt = 0; mt < 4; mt++)
#pragma unroll
      for (int nt = 0; nt < 4; nt++)
#pragma unroll
        for (int r = 0; r < 4; r++)
          Cp[(long)(m0 + wm * 64 + mt * 16 + orow + r) * N + (n0 + wn * 64 + nt * 16 + ocol)] =
              (_Float16)acc[mt][nt][r];
  } else {
    float* Cp = (float*)Cv + (long)b * sC;
#pragma unroll
    for (int mt = 0; mt < 4; mt++)
#pragma unroll
      for (int nt = 0; nt < 4; nt++)
#pragma unroll
        for (int r = 0; r < 4; r++)
          Cp[(long)(m0 + wm * 64 + mt * 16 + orow + r) * N + (n0 + wn * 64 + nt * 16 + ocol)] =
              acc[mt][nt][r];
  }
}

// ---------------------------------------------------------------------------
// In-place row softmax + optional fp16 copy of the result.
// One block per row of 2048 fp32; 8 elems/thread in regs.
// ---------------------------------------------------------------------------
template <bool EMIT_H>
__global__ __launch_bounds__(256)
void softmax_rows(float* __restrict__ S, _Float16* __restrict__ P)
{
  float* p = S + (long)blockIdx.x * 2048;
  const int tid = threadIdx.x, lane = tid & 63, wave = tid >> 6;

  float4 v0 = *(const float4*)(p + tid * 4);
  float4 v1 = *(const float4*)(p + 1024 + tid * 4);

  float mx = fmaxf(fmaxf(fmaxf(v0.x, v0.y), fmaxf(v0.z, v0.w)),
                   fmaxf(fmaxf(v1.x, v1.y), fmaxf(v1.z, v1.w)));
#pragma unroll
  for (int off = 32; off; off >>= 1) mx = fmaxf(mx, __shfl_down(mx, off, 64));

  __shared__ float red[8];
  if (lane == 0) red[wave] = mx;
  __syncthreads();
  mx = fmaxf(fmaxf(red[0], red[1]), fmaxf(red[2], red[3]));

  v0.x = __expf(v0.x - mx); v0.y = __expf(v0.y - mx);
  v0.z = __expf(v0.z - mx); v0.w = __expf(v0.w - mx);
  v1.x = __expf(v1.x - mx); v1.y = __expf(v1.y - mx);
  v1.z = __expf(v1.z - mx); v1.w = __expf(v1.w - mx);

  float s = v0.x + v0.y + v0.z + v0.w + v1.x + v1.y + v1.z + v1.w;
#pragma unroll
  for (int off = 32; off; off >>= 1) s += __shfl_down(s, off, 64);
  if (lane == 0) red[4 + wave] = s;
  __syncthreads();
  s = red[4] + red[5] + red[6] + red[7];

  float inv = 1.0f / s;
  v0.x *= inv; v0.y *= inv; v0.z *= inv; v0.w *= inv;
  v1.x *= inv; v1.y *= inv; v1.z *= inv; v1.w *= inv;
  *(float4*)(p + tid * 4) = v0;
  *(float4*)(p + 1024 + tid * 4) = v1;

  if constexpr (EMIT_H) {
    _Float16* ph = P + (long)blockIdx.x * 2048;
    half4v h0, h1;
    h0[0] = (_Float16)v0.x; h0[1] = (_Float16)v0.y;
    h0[2] = (_Float16)v0.z; h0[3] = (_Float16)v0.w;
    h1[0] = (_Float16)v1.x; h1[1] = (_Float16)v1.y;
    h1[2] = (_Float16)v1.z; h1[3] = (_Float16)v1.w;
    *(half4v*)(ph + tid * 4) = h0;
    *(half4v*)(ph + 1024 + tid * 4) = h1;
  }
}

// fp32 -> fp16 converts -------------------------------------------------------
__global__ __launch_bounds__(256)
void convert_q(const float4* __restrict__ q, half4v* __restrict__ qh)
{
  long i = (long)blockIdx.x * 256 + threadIdx.x;
  float4 a = q[i];
  half4v h;
  h[0] = (_Float16)a.x; h[1] = (_Float16)a.y; h[2] = (_Float16)a.z; h[3] = (_Float16)a.w;
  qh[i] = h;
}

// V transpose: v[b][k][e] fp32 -> vt[b][e][k] fp16 (for BT-layout context GEMM)
__global__ __launch_bounds__(256)
void transpose_v(const float* __restrict__ v, _Float16* __restrict__ vt)
{
  __shared__ float tile[32][33];
  const int b = blockIdx.z, kk = blockIdx.y * 32, ee = blockIdx.x * 32;
  const float* vp = v + (long)b * K_ * D_;
  _Float16* vtp = vt + (long)b * D_ * K_;
  const int tx = threadIdx.x & 31, ty = threadIdx.x >> 5;  // ty 0..7
#pragma unroll
  for (int i = 0; i < 32; i += 8)
    tile[ty + i][tx] = vp[(long)(kk + ty + i) * D_ + ee + tx];
  __syncthreads();
#pragma unroll
  for (int i = 0; i < 32; i += 8)
    vtp[(long)(ee + ty + i) * K_ + kk + tx] = (_Float16)tile[tx][ty + i];
}

// ---------------------------------------------------------------------------
extern "C" void kernel_launch(void* const* d_in, const int* in_sizes, int n_in,
                              void* d_out, int out_size, void* d_ws, size_t ws_size,
                              hipStream_t stream)
{
  const float* q = (const float*)d_in[0];   // [16,2048,512]
  const float* v = (const float*)d_in[1];   // [16,2048,512]
  const float* w = (const float*)d_in[2];   // [512,512]

  float* ctx    = (float*)d_out;                       // [16,2048,512]
  float* scores = ctx + (long)B_ * Q_ * D_;            // [16,2048,2048]

  const long nQD = (long)B_ * Q_ * D_;   // 16.78M halfs
  const long nKD = (long)B_ * K_ * D_;
  const long nDK = (long)B_ * D_ * K_;
  const long nQK = (long)B_ * Q_ * K_;   // 67.1M halfs

  // Fast path ws layout: wh(0.5MB) | vth(33.5MB) | X(134.2MB)
  //   X = qh|kh during scores phase, then ph (fp16 softmaxed P) afterwards.
  const size_t need_fast = (size_t)(512 * 512 + nDK + nQK) * sizeof(_Float16);
  const bool fast = ws_size >= need_fast;   // ws_size constant per session

  _Float16 *wh, *vth, *qh, *kh, *ph;
  if (fast) {
    wh  = (_Float16*)d_ws;
    vth = wh + 512 * 512;
    ph  = vth + nDK;
    qh  = ph;            // alias: qh/kh dead before ph is written
    kh  = qh + nQD;
  } else {               // R1 layout, a32 context fallback
    qh  = (_Float16*)d_ws;
    kh  = qh + nQD;
    vth = kh + nKD;
    wh  = vth + nDK;
    ph  = nullptr;
  }

  // 1. converts + transpose
  convert_q<<<16384, 256, 0, stream>>>((const float4*)q, (half4v*)qh);
  convert_q<<<256,   256, 0, stream>>>((const float4*)w, (half4v*)wh);
  transpose_v<<<dim3(D_ / 32, K_ / 32, B_), 256, 0, stream>>>(v, vth);

  // 2. keys[b] = v[b] (2048x512) * W^T (512x512) -> fp16
  gemm_a32_bt<true><<<dim3(D_ / 128, K_ / 128, B_), 256, 0, stream>>>(
      v, wh, kh, K_, D_, D_, D_, (long)K_ * D_, 0l, (long)K_ * D_);

  // 3. scores[b] = q[b] (2048x512) * keys[b]^T -> fp32 into d_out weights region
  gemm_bt_f16<false><<<dim3(K_ / 128, Q_ / 128, B_), 256, 0, stream>>>(
      qh, kh, scores, Q_, K_, D_, (long)Q_ * D_, (long)K_ * D_, (long)Q_ * K_);

  // 4. softmax over last dim, in place (+ fp16 P copy on fast path)
  if (fast)
    softmax_rows<true><<<B_ * Q_, 256, 0, stream>>>(scores, ph);
  else
    softmax_rows<false><<<B_ * Q_, 256, 0, stream>>>(scores, nullptr);

  // 5. context[b] = P[b] (2048x2048) * vt[b]^T (512x2048) -> fp32
  if (fast)
    gemm_bt_f16<false><<<dim3(D_ / 128, Q_ / 128, B_), 256, 0, stream>>>(
        ph, vth, ctx, Q_, D_, K_, (long)Q_ * K_, (long)D_ * K_, (long)Q_ * D_);
  else
    gemm_a32_bt<false><<<dim3(D_ / 128, Q_ / 128, B_), 256, 0, stream>>>(
        scores, vth, ctx, Q_, D_, K_, K_, (long)Q_ * K_, (long)D_ * K_, (long)Q_ * D_);
}